// Round 2
// baseline (2366.641 us; speedup 1.0000x reference)
//
#include <hip/hip_runtime.h>

// ---------------------------------------------------------------------------
// DR_CRN_Multicause fused forward
//   B=131072, N_CONF=512, H1=513(->544), N_REP=256, HP=257(->288), N_TREAT=64
// out (FLOAT32): pred_sel[B] | log_prop[B*64] | mmd[1] | cause[B]
// ws layout (bytes):
//   0        W1cb [544][512] bf16
//   557056   W2cb [256][544] bf16
//   835584   W1ob [544][512] bf16
//   1392640  W2ob [256][544] bf16
//   1671168  W1pb [288][256] bf16
//   1818624  W2pb [64][288]  bf16
//   1855488  Whb  [64][512]  bf16
//   1921024  b1cp [544] f32 | 1923200 b1op [544] f32 | 1925376 b1pp [288] f32
//   total 1926528 bytes
// ---------------------------------------------------------------------------

typedef __attribute__((ext_vector_type(8))) short bf16x8;
typedef __attribute__((ext_vector_type(4))) float f32x4;
typedef __attribute__((ext_vector_type(4))) short s16x4;

#define MFMA16 __builtin_amdgcn_mfma_f32_16x16x32_bf16

__device__ __forceinline__ short f2bf(float f) {
  union { float f; unsigned u; } v; v.f = f;
  return (short)((v.u + 0x7FFFu + ((v.u >> 16) & 1u)) >> 16);  // RNE
}

// ---- prep: convert+pad all weights/biases into ws (single launch) ----------
__global__ void prep_weights(const float* __restrict__ W1c, const float* __restrict__ W2c,
                             const float* __restrict__ W1o, const float* __restrict__ W2o,
                             const float* __restrict__ W1p, const float* __restrict__ W2p,
                             const float* __restrict__ Wh,
                             const float* __restrict__ b1c, const float* __restrict__ b1o,
                             const float* __restrict__ b1p,
                             char* __restrict__ ws) {
  int s = blockIdx.x * 256 + threadIdx.x;
  if (s < 960512) {                      // bf16 weight region (shorts)
    float v;
    if (s < 278528)      { int n = s >> 9,        k = s & 511;        v = (n < 513) ? W1c[n * 512 + k] : 0.f; }
    else if (s < 417792) { int i = s - 278528; int n = i / 544, k = i - n * 544; v = (k < 513) ? W2c[n * 513 + k] : 0.f; }
    else if (s < 696320) { int i = s - 417792; int n = i >> 9,  k = i & 511;     v = (n < 513) ? W1o[n * 512 + k] : 0.f; }
    else if (s < 835584) { int i = s - 696320; int n = i / 544, k = i - n * 544; v = (k < 513) ? W2o[n * 513 + k] : 0.f; }
    else if (s < 909312) { int i = s - 835584; int n = i >> 8,  k = i & 255;     v = (n < 257) ? W1p[n * 256 + k] : 0.f; }
    else if (s < 927744) { int i = s - 909312; int n = i / 288, k = i - n * 288; v = (k < 257) ? W2p[n * 257 + k] : 0.f; }
    else                 { v = Wh[s - 927744]; }
    ((short*)ws)[s] = f2bf(v);
  } else if (s < 961888) {               // padded f32 biases
    int j = s - 960512;
    float v;
    if (j < 544)       v = (j < 513) ? b1c[j] : 0.f;
    else if (j < 1088) { int q = j - 544;  v = (q < 513) ? b1o[q] : 0.f; }
    else               { int q = j - 1088; v = (q < 257) ? b1p[q] : 0.f; }
    ((float*)(ws + 1921024))[j] = v;
  }
}

// ---- fused main kernel: 64 rows/block, 4 waves, wave-private 16-row slices -
__global__ __launch_bounds__(256, 1)
void fused_main(const float* __restrict__ x, const int* __restrict__ cause,
                const char* __restrict__ ws,
                const float* __restrict__ b2c, const float* __restrict__ b2o,
                const float* __restrict__ b2p, const float* __restrict__ bh,
                float* __restrict__ out) {
  const short* W1cb = (const short*)(ws);
  const short* W2cb = (const short*)(ws + 557056);
  const short* W1ob = (const short*)(ws + 835584);
  const short* W2ob = (const short*)(ws + 1392640);
  const short* W1pb = (const short*)(ws + 1671168);
  const short* W2pb = (const short*)(ws + 1818624);
  const short* Whb  = (const short*)(ws + 1855488);
  const float* b1cp = (const float*)(ws + 1921024);
  const float* b1op = (const float*)(ws + 1923200);
  const float* b1pp = (const float*)(ws + 1925376);

  // LDS regions (byte offsets); 138240 total dynamic
  extern __shared__ __align__(16) char lds[];
  short* Xs    = (short*)lds;             // [64][520] bf16   (phase A)
  short* Cs    = (short*)lds;             // [64][264] bf16   (after X dead)
  short* Os    = (short*)(lds + 33792);   // [64][264] bf16
  short* Hs    = (short*)(lds + 67584);   // [64][552] bf16   (H_c then H_o)
  float* headB = (float*)(lds + 67584);   // [64][68] f32     (after H_o dead)
  short* Hp    = (short*)(lds + 67584);   // [64][296] bf16   (after headB dead)

  const int tid  = threadIdx.x;
  const int lane = tid & 63;
  const int wid  = tid >> 6;
  const int l15  = lane & 15;
  const int l4   = lane >> 4;            // 0..3
  const int rbase = wid * 16;            // wave's row base within tile
  const size_t grow0 = (size_t)blockIdx.x * 64;

  // ---- stage X (wave loads its own 16 rows; f32 -> bf16) ----
  {
    const float4* xsrc = (const float4*)(x + (grow0 + rbase) * 512);
    for (int i = lane; i < 2048; i += 64) {   // 16 rows * 128 float4
      int r = i >> 7, c = i & 127;
      float4 v = xsrc[r * 128 + c];
      s16x4 p;
      p.x = f2bf(v.x); p.y = f2bf(v.y); p.z = f2bf(v.z); p.w = f2bf(v.w);
      *(s16x4*)&Xs[(rbase + r) * 520 + c * 4] = p;
    }
  }

  // ---- hoist X A-fragments: lane l holds A[l&15][(l>>4)*8 + j], k-tile kt ----
  bf16x8 ax[16];
  #pragma unroll
  for (int kt = 0; kt < 16; ++kt)
    ax[kt] = *(const bf16x8*)&Xs[(rbase + l15) * 520 + kt * 32 + l4 * 8];

  __syncthreads();   // (1) all waves consumed X into regs before region0 reuse

  // ---- layer1: H[64][544] = relu(X @ W1^T + b1) -> Hs (wave-private rows) --
  auto L1 = [&](const short* __restrict__ W, const float* __restrict__ bpad) {
    #pragma unroll 1
    for (int nt = 0; nt < 34; nt += 2) {
      f32x4 a0 = {0.f, 0.f, 0.f, 0.f}, a1 = {0.f, 0.f, 0.f, 0.f};
      const short* w0 = W + (nt * 16 + l15) * 512 + l4 * 8;
      #pragma unroll
      for (int kt = 0; kt < 16; ++kt) {
        bf16x8 b0 = *(const bf16x8*)(w0 + kt * 32);
        bf16x8 b1 = *(const bf16x8*)(w0 + 8192 + kt * 32);   // +16 rows
        a0 = MFMA16(ax[kt], b0, a0, 0, 0, 0);
        a1 = MFMA16(ax[kt], b1, a1, 0, 0, 0);
      }
      float bi0 = bpad[nt * 16 + l15], bi1 = bpad[nt * 16 + 16 + l15];
      short* hrow = &Hs[(rbase + l4 * 4) * 552 + nt * 16 + l15];
      #pragma unroll
      for (int r = 0; r < 4; ++r) {
        hrow[r * 552]      = f2bf(fmaxf(a0[r] + bi0, 0.f));
        hrow[r * 552 + 16] = f2bf(fmaxf(a1[r] + bi1, 0.f));
      }
    }
  };

  // ---- layer2: rep[64][256] = Hs @ W2^T + b2 (kept in registers) ----
  auto L2 = [&](const short* __restrict__ W, const float* __restrict__ b2, f32x4* rep) {
    bf16x8 ah[17];
    #pragma unroll
    for (int kt = 0; kt < 17; ++kt)
      ah[kt] = *(const bf16x8*)&Hs[(rbase + l15) * 552 + kt * 32 + l4 * 8];
    #pragma unroll
    for (int nt = 0; nt < 16; nt += 2) {
      f32x4 a0 = {0.f, 0.f, 0.f, 0.f}, a1 = {0.f, 0.f, 0.f, 0.f};
      const short* w0 = W + (nt * 16 + l15) * 544 + l4 * 8;
      #pragma unroll
      for (int kt = 0; kt < 17; ++kt) {
        a0 = MFMA16(ah[kt], *(const bf16x8*)(w0 + kt * 32), a0, 0, 0, 0);
        a1 = MFMA16(ah[kt], *(const bf16x8*)(w0 + 8704 + kt * 32), a1, 0, 0, 0);
      }
      float bi0 = b2[nt * 16 + l15], bi1 = b2[nt * 16 + 16 + l15];
      #pragma unroll
      for (int r = 0; r < 4; ++r) { a0[r] += bi0; a1[r] += bi1; }
      rep[nt] = a0; rep[nt + 1] = a1;
    }
  };

  L1(W1cb, b1cp);                 // Hs = H_c
  f32x4 crep[16];
  L2(W2cb, b2c, crep);            // crep in regs
  L1(W1ob, b1op);                 // Hs = H_o (crep still live)

  // X region dead -> store confounder rep as bf16 (Cs)
  #pragma unroll
  for (int nt = 0; nt < 16; ++nt) {
    #pragma unroll
    for (int r = 0; r < 4; ++r)
      Cs[(rbase + l4 * 4 + r) * 264 + nt * 16 + l15] = f2bf(crep[nt][r]);
  }
  f32x4 orep[16];
  L2(W2ob, b2o, orep);
  #pragma unroll
  for (int nt = 0; nt < 16; ++nt) {
    #pragma unroll
    for (int r = 0; r < 4; ++r)
      Os[(rbase + l4 * 4 + r) * 264 + nt * 16 + l15] = f2bf(orep[nt][r]);
  }

  // ---- head: pred[64][64] = [C|O] @ Wh^T ----
  f32x4 hacc[4] = {{0.f,0.f,0.f,0.f},{0.f,0.f,0.f,0.f},{0.f,0.f,0.f,0.f},{0.f,0.f,0.f,0.f}};
  {
    bf16x8 acf[16];
    #pragma unroll
    for (int kt = 0; kt < 8; ++kt) {
      acf[kt]     = *(const bf16x8*)&Cs[(rbase + l15) * 264 + kt * 32 + l4 * 8];
      acf[kt + 8] = *(const bf16x8*)&Os[(rbase + l15) * 264 + kt * 32 + l4 * 8];
    }
    #pragma unroll
    for (int nt = 0; nt < 4; ++nt) {
      const short* w0 = Whb + (nt * 16 + l15) * 512 + l4 * 8;
      #pragma unroll
      for (int kt = 0; kt < 16; ++kt)
        hacc[nt] = MFMA16(acf[kt], *(const bf16x8*)(w0 + kt * 32), hacc[nt], 0, 0, 0);
    }
  }
  __syncthreads();   // (2) all waves finished reading Hs(H_o) before headB overwrite

  #pragma unroll
  for (int nt = 0; nt < 4; ++nt) {
    #pragma unroll
    for (int r = 0; r < 4; ++r)
      headB[(rbase + l4 * 4 + r) * 68 + nt * 16 + l15] = hacc[nt][r];
  }
  // one-hot selection + cause passthrough (lanes 0..15 handle the wave's rows)
  if (lane < 16) {
    int row = rbase + lane;
    size_t gr = grow0 + row;
    int cv = cause[gr];
    float val = headB[row * 68 + cv] + bh[cv];
    out[gr] = val;
    out[(size_t)8519681 + gr] = (float)cv;   // cause after mmd scalar
  }
  __syncthreads();   // (3) selection reads done before Hp overwrites region1

  // ---- propensity L1: Hp[64][288] = relu(Cs @ W1p^T + b1p) ----
  {
    bf16x8 ac[8];
    #pragma unroll
    for (int kt = 0; kt < 8; ++kt)
      ac[kt] = *(const bf16x8*)&Cs[(rbase + l15) * 264 + kt * 32 + l4 * 8];
    #pragma unroll 1
    for (int nt = 0; nt < 18; nt += 2) {
      f32x4 a0 = {0.f, 0.f, 0.f, 0.f}, a1 = {0.f, 0.f, 0.f, 0.f};
      const short* w0 = W1pb + (nt * 16 + l15) * 256 + l4 * 8;
      #pragma unroll
      for (int kt = 0; kt < 8; ++kt) {
        a0 = MFMA16(ac[kt], *(const bf16x8*)(w0 + kt * 32), a0, 0, 0, 0);
        a1 = MFMA16(ac[kt], *(const bf16x8*)(w0 + 4096 + kt * 32), a1, 0, 0, 0);
      }
      float bi0 = b1pp[nt * 16 + l15], bi1 = b1pp[nt * 16 + 16 + l15];
      short* hrow = &Hp[(rbase + l4 * 4) * 296 + nt * 16 + l15];
      #pragma unroll
      for (int r = 0; r < 4; ++r) {
        hrow[r * 296]      = f2bf(fmaxf(a0[r] + bi0, 0.f));
        hrow[r * 296 + 16] = f2bf(fmaxf(a1[r] + bi1, 0.f));
      }
    }
  }

  // ---- propensity L2 + log_softmax ----
  f32x4 pl[4];
  {
    bf16x8 ahp[9];
    #pragma unroll
    for (int kt = 0; kt < 9; ++kt)
      ahp[kt] = *(const bf16x8*)&Hp[(rbase + l15) * 296 + kt * 32 + l4 * 8];
    #pragma unroll
    for (int nt = 0; nt < 4; ++nt) {
      f32x4 a0 = {0.f, 0.f, 0.f, 0.f};
      const short* w0 = W2pb + (nt * 16 + l15) * 288 + l4 * 8;
      #pragma unroll
      for (int kt = 0; kt < 9; ++kt)
        a0 = MFMA16(ahp[kt], *(const bf16x8*)(w0 + kt * 32), a0, 0, 0, 0);
      float bi = b2p[nt * 16 + l15];
      #pragma unroll
      for (int r = 0; r < 4; ++r) a0[r] += bi;
      pl[nt] = a0;
    }
  }
  // row-wise log_softmax: row's 64 cols live in this lane's 16-lane group x 4 regs
  #pragma unroll
  for (int r = 0; r < 4; ++r) {
    float m = fmaxf(fmaxf(pl[0][r], pl[1][r]), fmaxf(pl[2][r], pl[3][r]));
    m = fmaxf(m, __shfl_xor(m, 1, 64));
    m = fmaxf(m, __shfl_xor(m, 2, 64));
    m = fmaxf(m, __shfl_xor(m, 4, 64));
    m = fmaxf(m, __shfl_xor(m, 8, 64));
    float s = __expf(pl[0][r] - m) + __expf(pl[1][r] - m)
            + __expf(pl[2][r] - m) + __expf(pl[3][r] - m);
    s += __shfl_xor(s, 1, 64);
    s += __shfl_xor(s, 2, 64);
    s += __shfl_xor(s, 4, 64);
    s += __shfl_xor(s, 8, 64);
    float lse = m + __logf(s);
    size_t gr = grow0 + rbase + l4 * 4 + r;
    float* o1 = out + 131072 + gr * 64;
    #pragma unroll
    for (int nt = 0; nt < 4; ++nt)
      o1[nt * 16 + l15] = pl[nt][r] - lse;
  }
  if (blockIdx.x == 0 && tid == 0) out[8519680] = 0.0f;   // mmd = 0.0
}

extern "C" void kernel_launch(void* const* d_in, const int* in_sizes, int n_in,
                              void* d_out, int out_size, void* d_ws, size_t ws_size,
                              hipStream_t stream) {
  (void)in_sizes; (void)n_in; (void)out_size; (void)ws_size;
  const float* x    = (const float*)d_in[0];
  const int*   cause= (const int*)  d_in[1];
  const float* W1c  = (const float*)d_in[2];
  const float* b1c  = (const float*)d_in[3];
  const float* W2c  = (const float*)d_in[4];
  const float* b2c  = (const float*)d_in[5];
  const float* W1o  = (const float*)d_in[6];
  const float* b1o  = (const float*)d_in[7];
  const float* W2o  = (const float*)d_in[8];
  const float* b2o  = (const float*)d_in[9];
  const float* W1p  = (const float*)d_in[10];
  const float* b1p  = (const float*)d_in[11];
  const float* W2p  = (const float*)d_in[12];
  const float* b2p  = (const float*)d_in[13];
  const float* Wh   = (const float*)d_in[14];
  const float* bh   = (const float*)d_in[15];
  char* ws = (char*)d_ws;

  prep_weights<<<3758, 256, 0, stream>>>(W1c, W2c, W1o, W2o, W1p, W2p, Wh,
                                         b1c, b1o, b1p, ws);

  (void)hipFuncSetAttribute((const void*)fused_main,
                            hipFuncAttributeMaxDynamicSharedMemorySize, 138240);
  fused_main<<<2048, 256, 138240, stream>>>(x, cause, ws, b2c, b2o, b2p, bh,
                                            (float*)d_out);
}

// Round 4
// 1372.048 us; speedup vs baseline: 1.7249x; 1.7249x over previous
//
#include <hip/hip_runtime.h>

// ---------------------------------------------------------------------------
// DR_CRN_Multicause fused forward — round 4: nt-split waves + full A-hoist
//   (round-3 design; fixed nontemporal-load type + acc[rg][r] indexing bug)
//   B=131072, N_CONF=512, H1=513(->544), N_REP=256, HP=257(->288), N_TREAT=64
// out (FLOAT32): pred_sel[B] | log_prop[B*64] | mmd[1] | cause[B]
// Block = 64 rows, 4 waves. L1/L2/propL1 are nt-split (each wave owns all 64
// rows, a quarter of output cols -> weights loaded once per block, each B-frag
// feeds 4 MFMAs). head/propL2/softmax stay row-split (tiny weights).
// ---------------------------------------------------------------------------

typedef __attribute__((ext_vector_type(8))) short bf16x8;
typedef __attribute__((ext_vector_type(4))) float f32x4;
typedef __attribute__((ext_vector_type(4))) short s16x4;

#define MFMA16 __builtin_amdgcn_mfma_f32_16x16x32_bf16

__device__ __forceinline__ short f2bf(float f) {
  union { float f; unsigned u; } v; v.f = f;
  return (short)((v.u + 0x7FFFu + ((v.u >> 16) & 1u)) >> 16);  // RNE
}

// ---- prep: convert+pad all weights/biases into ws (single launch) ----------
__global__ void prep_weights(const float* __restrict__ W1c, const float* __restrict__ W2c,
                             const float* __restrict__ W1o, const float* __restrict__ W2o,
                             const float* __restrict__ W1p, const float* __restrict__ W2p,
                             const float* __restrict__ Wh,
                             const float* __restrict__ b1c, const float* __restrict__ b1o,
                             const float* __restrict__ b1p,
                             char* __restrict__ ws) {
  int s = blockIdx.x * 256 + threadIdx.x;
  if (s < 960512) {                      // bf16 weight region (shorts)
    float v;
    if (s < 278528)      { int n = s >> 9,        k = s & 511;        v = (n < 513) ? W1c[n * 512 + k] : 0.f; }
    else if (s < 417792) { int i = s - 278528; int n = i / 544, k = i - n * 544; v = (k < 513) ? W2c[n * 513 + k] : 0.f; }
    else if (s < 696320) { int i = s - 417792; int n = i >> 9,  k = i & 511;     v = (n < 513) ? W1o[n * 512 + k] : 0.f; }
    else if (s < 835584) { int i = s - 696320; int n = i / 544, k = i - n * 544; v = (k < 513) ? W2o[n * 513 + k] : 0.f; }
    else if (s < 909312) { int i = s - 835584; int n = i >> 8,  k = i & 255;     v = (n < 257) ? W1p[n * 256 + k] : 0.f; }
    else if (s < 927744) { int i = s - 909312; int n = i / 288, k = i - n * 288; v = (k < 257) ? W2p[n * 257 + k] : 0.f; }
    else                 { v = Wh[s - 927744]; }
    ((short*)ws)[s] = f2bf(v);
  } else if (s < 961888) {               // padded f32 biases
    int j = s - 960512;
    float v;
    if (j < 544)       v = (j < 513) ? b1c[j] : 0.f;
    else if (j < 1088) { int q = j - 544;  v = (q < 513) ? b1o[q] : 0.f; }
    else               { int q = j - 1088; v = (q < 257) ? b1p[q] : 0.f; }
    ((float*)(ws + 1921024))[j] = v;
  }
}

__global__ __launch_bounds__(256, 1)
void fused_main(const float* __restrict__ x, const int* __restrict__ cause,
                const char* __restrict__ ws,
                const float* __restrict__ b2c, const float* __restrict__ b2o,
                const float* __restrict__ b2p, const float* __restrict__ bh,
                float* __restrict__ out) {
  const short* W1cb = (const short*)(ws);
  const short* W2cb = (const short*)(ws + 557056);
  const short* W1ob = (const short*)(ws + 835584);
  const short* W2ob = (const short*)(ws + 1392640);
  const short* W1pb = (const short*)(ws + 1671168);
  const short* W2pb = (const short*)(ws + 1818624);
  const short* Whb  = (const short*)(ws + 1855488);
  const float* b1cp = (const float*)(ws + 1921024);
  const float* b1op = (const float*)(ws + 1923200);
  const float* b1pp = (const float*)(ws + 1925376);

  // LDS regions (byte offsets); 138240 total dynamic. Timeline overlays:
  //   region0 [0,66560): Xs[64][520] -> (dead after hoist) Cs[64][264]@0
  //   region1 [33792,67584): Os[64][264] (written after Xs dead)
  //   region2 [67584,138240): Hs[64][552] -> headB[64][68]f32 -> Hp[64][296]
  extern __shared__ __align__(16) char lds[];
  short* Xs    = (short*)lds;
  short* Cs    = (short*)lds;
  short* Os    = (short*)(lds + 33792);
  short* Hs    = (short*)(lds + 67584);
  float* headB = (float*)(lds + 67584);
  short* Hp    = (short*)(lds + 67584);

  const int tid  = threadIdx.x;
  const int lane = tid & 63;
  const int wid  = tid >> 6;
  const int l15  = lane & 15;
  const int l4   = lane >> 4;            // 0..3
  const int rbase = wid * 16;            // row-split base (head/propL2 only)
  const size_t grow0 = (size_t)blockIdx.x * 64;

  // ---- stage X block-wide (f32 -> bf16), nontemporal to keep weights in L2 -
  {
    const f32x4* xsrc = (const f32x4*)(x + grow0 * 512);
    for (int i = tid; i < 8192; i += 256) {   // 64 rows * 128 float4
      f32x4 v = __builtin_nontemporal_load(xsrc + i);
      int r = i >> 7, c = i & 127;
      s16x4 p;
      p.x = f2bf(v.x); p.y = f2bf(v.y); p.z = f2bf(v.z); p.w = f2bf(v.w);
      *(s16x4*)&Xs[r * 520 + c * 4] = p;
    }
  }
  __syncthreads();   // B0: X fully staged

  // ---- hoist ALL 64 rows' A-fragments: ax[rg][kt], 256 VGPRs ----
  bf16x8 ax[4][16];
  #pragma unroll
  for (int rg = 0; rg < 4; ++rg)
    #pragma unroll
    for (int kt = 0; kt < 16; ++kt)
      ax[rg][kt] = *(const bf16x8*)&Xs[(rg * 16 + l15) * 520 + kt * 32 + l4 * 8];

  // ---- L1 (nt-split, 2-deep register double-buffer on B-frags) ----
  auto L1 = [&](const short* __restrict__ W, const float* __restrict__ bpad) {
    bf16x8 bA[16], bB[16];
    auto LD = [&](bf16x8 (&b)[16], int nt) {
      const short* w0 = W + (nt * 16 + l15) * 512 + l4 * 8;
      #pragma unroll
      for (int kt = 0; kt < 16; ++kt) b[kt] = *(const bf16x8*)(w0 + kt * 32);
    };
    auto DO = [&](int nt, bf16x8 (&b)[16]) {
      f32x4 acc[4] = {{0.f,0.f,0.f,0.f},{0.f,0.f,0.f,0.f},{0.f,0.f,0.f,0.f},{0.f,0.f,0.f,0.f}};
      #pragma unroll
      for (int kt = 0; kt < 16; ++kt)
        #pragma unroll
        for (int rg = 0; rg < 4; ++rg)
          acc[rg] = MFMA16(ax[rg][kt], b[kt], acc[rg], 0, 0, 0);
      float bi = bpad[nt * 16 + l15];
      #pragma unroll
      for (int rg = 0; rg < 4; ++rg)
        #pragma unroll
        for (int r = 0; r < 4; ++r)
          Hs[(rg * 16 + l4 * 4 + r) * 552 + nt * 16 + l15] = f2bf(fmaxf(acc[rg][r] + bi, 0.f));
    };
    int nt = wid;
    LD(bA, nt);
    for (;;) {
      int n2 = nt + 4;
      if (n2 < 34) LD(bB, n2);
      DO(nt, bA);
      if (n2 >= 34) break;
      int n3 = n2 + 4;
      if (n3 < 34) LD(bA, n3);
      DO(n2, bB);
      if (n3 >= 34) break;
      nt = n3;
    }
  };

  // ---- L2 (nt-split, 4 nts/wave, A-frags re-read from Hs per nt) ----
  auto L2 = [&](const short* __restrict__ W, const float* __restrict__ b2,
                short* __restrict__ dst) {
    #pragma unroll 1
    for (int i = 0; i < 4; ++i) {
      int nt = wid + i * 4;
      bf16x8 bw[17];
      const short* w0 = W + (nt * 16 + l15) * 544 + l4 * 8;
      #pragma unroll
      for (int kt = 0; kt < 17; ++kt) bw[kt] = *(const bf16x8*)(w0 + kt * 32);
      f32x4 acc[4] = {{0.f,0.f,0.f,0.f},{0.f,0.f,0.f,0.f},{0.f,0.f,0.f,0.f},{0.f,0.f,0.f,0.f}};
      #pragma unroll
      for (int kt = 0; kt < 17; ++kt)
        #pragma unroll
        for (int rg = 0; rg < 4; ++rg) {
          bf16x8 a = *(const bf16x8*)&Hs[(rg * 16 + l15) * 552 + kt * 32 + l4 * 8];
          acc[rg] = MFMA16(a, bw[kt], acc[rg], 0, 0, 0);
        }
      float bi = b2[nt * 16 + l15];
      #pragma unroll
      for (int rg = 0; rg < 4; ++rg)
        #pragma unroll
        for (int r = 0; r < 4; ++r)
          dst[(rg * 16 + l4 * 4 + r) * 264 + nt * 16 + l15] = f2bf(acc[rg][r] + bi);
    }
  };

  L1(W1cb, b1cp);                 // Hs = H_c
  __syncthreads();                // B1: H_c complete (cross-wave cols)
  L2(W2cb, b2c, Cs);              // Cs = confounder rep (region0; Xs dead)
  __syncthreads();                // B2: Hs reads done -> L1o may overwrite
  L1(W1ob, b1op);                 // Hs = H_o
  __syncthreads();                // B3: H_o complete
  L2(W2ob, b2o, Os);              // Os = outcome rep
  __syncthreads();                // B4: Cs/Os complete; Hs dead

  // ---- head (row-split): pred[16 own rows][64] = [C|O] @ Wh^T ----
  f32x4 hacc[4] = {{0.f,0.f,0.f,0.f},{0.f,0.f,0.f,0.f},{0.f,0.f,0.f,0.f},{0.f,0.f,0.f,0.f}};
  {
    bf16x8 acf[16];
    #pragma unroll
    for (int kt = 0; kt < 8; ++kt) {
      acf[kt]     = *(const bf16x8*)&Cs[(rbase + l15) * 264 + kt * 32 + l4 * 8];
      acf[kt + 8] = *(const bf16x8*)&Os[(rbase + l15) * 264 + kt * 32 + l4 * 8];
    }
    #pragma unroll
    for (int nt = 0; nt < 4; ++nt) {
      const short* w0 = Whb + (nt * 16 + l15) * 512 + l4 * 8;
      #pragma unroll
      for (int kt = 0; kt < 16; ++kt)
        hacc[nt] = MFMA16(acf[kt], *(const bf16x8*)(w0 + kt * 32), hacc[nt], 0, 0, 0);
    }
  }
  // headB overlays Hs region (dead after B4); wave writes its own 16 rows
  #pragma unroll
  for (int nt = 0; nt < 4; ++nt)
    #pragma unroll
    for (int r = 0; r < 4; ++r)
      headB[(rbase + l4 * 4 + r) * 68 + nt * 16 + l15] = hacc[nt][r];
  // one-hot selection + cause passthrough (wave-local rows; no barrier needed)
  if (lane < 16) {
    int row = rbase + lane;
    size_t gr = grow0 + row;
    int cv = cause[gr];
    out[gr] = headB[row * 68 + cv] + bh[cv];
    out[(size_t)8519681 + gr] = (float)cv;
  }
  __syncthreads();                // B5: headB reads done -> Hp may overwrite

  // ---- propensity L1 (nt-split, 18 nts, 2-deep B double-buffer) ----
  {
    bf16x8 ac[4][8];
    #pragma unroll
    for (int rg = 0; rg < 4; ++rg)
      #pragma unroll
      for (int kt = 0; kt < 8; ++kt)
        ac[rg][kt] = *(const bf16x8*)&Cs[(rg * 16 + l15) * 264 + kt * 32 + l4 * 8];
    bf16x8 bA[8], bB[8];
    auto LDp = [&](bf16x8 (&b)[8], int nt) {
      const short* w0 = W1pb + (nt * 16 + l15) * 256 + l4 * 8;
      #pragma unroll
      for (int kt = 0; kt < 8; ++kt) b[kt] = *(const bf16x8*)(w0 + kt * 32);
    };
    auto DOp = [&](int nt, bf16x8 (&b)[8]) {
      f32x4 acc[4] = {{0.f,0.f,0.f,0.f},{0.f,0.f,0.f,0.f},{0.f,0.f,0.f,0.f},{0.f,0.f,0.f,0.f}};
      #pragma unroll
      for (int kt = 0; kt < 8; ++kt)
        #pragma unroll
        for (int rg = 0; rg < 4; ++rg)
          acc[rg] = MFMA16(ac[rg][kt], b[kt], acc[rg], 0, 0, 0);
      float bi = b1pp[nt * 16 + l15];
      #pragma unroll
      for (int rg = 0; rg < 4; ++rg)
        #pragma unroll
        for (int r = 0; r < 4; ++r)
          Hp[(rg * 16 + l4 * 4 + r) * 296 + nt * 16 + l15] = f2bf(fmaxf(acc[rg][r] + bi, 0.f));
    };
    int nt = wid;
    LDp(bA, nt);
    for (;;) {
      int n2 = nt + 4;
      if (n2 < 18) LDp(bB, n2);
      DOp(nt, bA);
      if (n2 >= 18) break;
      int n3 = n2 + 4;
      if (n3 < 18) LDp(bA, n3);
      DOp(n2, bB);
      if (n3 >= 18) break;
      nt = n3;
    }
  }
  __syncthreads();                // B6: Hp complete (cross-wave cols)

  // ---- propensity L2 + log_softmax (row-split, wave-local rows) ----
  f32x4 pl[4];
  {
    bf16x8 ahp[9];
    #pragma unroll
    for (int kt = 0; kt < 9; ++kt)
      ahp[kt] = *(const bf16x8*)&Hp[(rbase + l15) * 296 + kt * 32 + l4 * 8];
    #pragma unroll
    for (int nt = 0; nt < 4; ++nt) {
      f32x4 a0 = {0.f, 0.f, 0.f, 0.f};
      const short* w0 = W2pb + (nt * 16 + l15) * 288 + l4 * 8;
      #pragma unroll
      for (int kt = 0; kt < 9; ++kt)
        a0 = MFMA16(ahp[kt], *(const bf16x8*)(w0 + kt * 32), a0, 0, 0, 0);
      float bi = b2p[nt * 16 + l15];
      #pragma unroll
      for (int r = 0; r < 4; ++r) a0[r] += bi;
      pl[nt] = a0;
    }
  }
  #pragma unroll
  for (int r = 0; r < 4; ++r) {
    float m = fmaxf(fmaxf(pl[0][r], pl[1][r]), fmaxf(pl[2][r], pl[3][r]));
    m = fmaxf(m, __shfl_xor(m, 1, 64));
    m = fmaxf(m, __shfl_xor(m, 2, 64));
    m = fmaxf(m, __shfl_xor(m, 4, 64));
    m = fmaxf(m, __shfl_xor(m, 8, 64));
    float s = __expf(pl[0][r] - m) + __expf(pl[1][r] - m)
            + __expf(pl[2][r] - m) + __expf(pl[3][r] - m);
    s += __shfl_xor(s, 1, 64);
    s += __shfl_xor(s, 2, 64);
    s += __shfl_xor(s, 4, 64);
    s += __shfl_xor(s, 8, 64);
    float lse = m + __logf(s);
    size_t gr = grow0 + rbase + l4 * 4 + r;
    float* o1 = out + 131072 + gr * 64;
    #pragma unroll
    for (int nt = 0; nt < 4; ++nt)
      o1[nt * 16 + l15] = pl[nt][r] - lse;
  }
  if (blockIdx.x == 0 && tid == 0) out[8519680] = 0.0f;   // mmd
}

extern "C" void kernel_launch(void* const* d_in, const int* in_sizes, int n_in,
                              void* d_out, int out_size, void* d_ws, size_t ws_size,
                              hipStream_t stream) {
  (void)in_sizes; (void)n_in; (void)out_size; (void)ws_size;
  const float* x    = (const float*)d_in[0];
  const int*   cause= (const int*)  d_in[1];
  const float* W1c  = (const float*)d_in[2];
  const float* b1c  = (const float*)d_in[3];
  const float* W2c  = (const float*)d_in[4];
  const float* b2c  = (const float*)d_in[5];
  const float* W1o  = (const float*)d_in[6];
  const float* b1o  = (const float*)d_in[7];
  const float* W2o  = (const float*)d_in[8];
  const float* b2o  = (const float*)d_in[9];
  const float* W1p  = (const float*)d_in[10];
  const float* b1p  = (const float*)d_in[11];
  const float* W2p  = (const float*)d_in[12];
  const float* b2p  = (const float*)d_in[13];
  const float* Wh   = (const float*)d_in[14];
  const float* bh   = (const float*)d_in[15];
  char* ws = (char*)d_ws;

  prep_weights<<<3758, 256, 0, stream>>>(W1c, W2c, W1o, W2o, W1p, W2p, Wh,
                                         b1c, b1o, b1p, ws);

  (void)hipFuncSetAttribute((const void*)fused_main,
                            hipFuncAttributeMaxDynamicSharedMemorySize, 138240);
  fused_main<<<2048, 256, 138240, stream>>>(x, cause, ws, b2c, b2o, b2p, bh,
                                            (float*)d_out);
}

// Round 5
// 941.941 us; speedup vs baseline: 2.5125x; 1.4566x over previous
//
#include <hip/hip_runtime.h>

// ---------------------------------------------------------------------------
// DR_CRN_Multicause fused forward — round 5: nt-split + nt-PAIRED tiles,
//   A-operands from LDS (no big reg hoist -> no scratch spill).
//   B=131072, N_CONF=512, H1=513(->544), N_REP=256, HP=257(->288), N_TREAT=64
// out (FLOAT32): pred_sel[B] | log_prop[B*64] | mmd[1] | cause[B]
// Block = 64 rows, 4 waves. Weights read once per block (nt-split); each
// B-fragment pair feeds 8 MFMAs per kt from one LDS A-read per rg.
// LDS (138240 B): Cs[0,33792) | Os[33792,67584) | Hs[67584,138240)
//   Xs[64][520] overlays [0,66560) (alive stage -> end L1o; Cs flushed after)
//   headB/Hp overlay Hs region after L2o.
// ---------------------------------------------------------------------------

typedef __attribute__((ext_vector_type(8))) short bf16x8;
typedef __attribute__((ext_vector_type(4))) float f32x4;
typedef __attribute__((ext_vector_type(4))) short s16x4;

#define MFMA16 __builtin_amdgcn_mfma_f32_16x16x32_bf16

__device__ __forceinline__ short f2bf(float f) {
  union { float f; unsigned u; } v; v.f = f;
  return (short)((v.u + 0x7FFFu + ((v.u >> 16) & 1u)) >> 16);  // RNE
}

// ---- prep: convert+pad all weights/biases into ws (single launch) ----------
__global__ void prep_weights(const float* __restrict__ W1c, const float* __restrict__ W2c,
                             const float* __restrict__ W1o, const float* __restrict__ W2o,
                             const float* __restrict__ W1p, const float* __restrict__ W2p,
                             const float* __restrict__ Wh,
                             const float* __restrict__ b1c, const float* __restrict__ b1o,
                             const float* __restrict__ b1p,
                             char* __restrict__ ws) {
  int s = blockIdx.x * 256 + threadIdx.x;
  if (s < 960512) {                      // bf16 weight region (shorts)
    float v;
    if (s < 278528)      { int n = s >> 9,        k = s & 511;        v = (n < 513) ? W1c[n * 512 + k] : 0.f; }
    else if (s < 417792) { int i = s - 278528; int n = i / 544, k = i - n * 544; v = (k < 513) ? W2c[n * 513 + k] : 0.f; }
    else if (s < 696320) { int i = s - 417792; int n = i >> 9,  k = i & 511;     v = (n < 513) ? W1o[n * 512 + k] : 0.f; }
    else if (s < 835584) { int i = s - 696320; int n = i / 544, k = i - n * 544; v = (k < 513) ? W2o[n * 513 + k] : 0.f; }
    else if (s < 909312) { int i = s - 835584; int n = i >> 8,  k = i & 255;     v = (n < 257) ? W1p[n * 256 + k] : 0.f; }
    else if (s < 927744) { int i = s - 909312; int n = i / 288, k = i - n * 288; v = (k < 257) ? W2p[n * 257 + k] : 0.f; }
    else                 { v = Wh[s - 927744]; }
    ((short*)ws)[s] = f2bf(v);
  } else if (s < 961888) {               // padded f32 biases
    int j = s - 960512;
    float v;
    if (j < 544)       v = (j < 513) ? b1c[j] : 0.f;
    else if (j < 1088) { int q = j - 544;  v = (q < 513) ? b1o[q] : 0.f; }
    else               { int q = j - 1088; v = (q < 257) ? b1p[q] : 0.f; }
    ((float*)(ws + 1921024))[j] = v;
  }
}

// paired 2x16-col tile: B in regs, A from LDS; acc0 = cols [nt0*16,+16),
// acc1 = cols [nt0*16+16,+16), all 64 rows.
template<int NKT>
__device__ __forceinline__ void pair_mm(const short* __restrict__ W, int ldw,
                                        const short* __restrict__ A, int lda,
                                        int nt0, int l15, int l4,
                                        f32x4 (&acc0)[4], f32x4 (&acc1)[4]) {
  bf16x8 b0[NKT], b1[NKT];
  const short* w0 = W + (nt0 * 16 + l15) * ldw + l4 * 8;
  const short* w1 = w0 + 16 * ldw;
  #pragma unroll
  for (int kt = 0; kt < NKT; ++kt) {
    b0[kt] = *(const bf16x8*)(w0 + kt * 32);
    b1[kt] = *(const bf16x8*)(w1 + kt * 32);
  }
  #pragma unroll
  for (int rg = 0; rg < 4; ++rg) {
    acc0[rg] = (f32x4){0.f, 0.f, 0.f, 0.f};
    acc1[rg] = (f32x4){0.f, 0.f, 0.f, 0.f};
  }
  #pragma unroll
  for (int kt = 0; kt < NKT; ++kt) {
    #pragma unroll
    for (int rg = 0; rg < 4; ++rg) {
      bf16x8 a = *(const bf16x8*)(A + (rg * 16 + l15) * lda + kt * 32 + l4 * 8);
      acc0[rg] = MFMA16(a, b0[kt], acc0[rg], 0, 0, 0);
      acc1[rg] = MFMA16(a, b1[kt], acc1[rg], 0, 0, 0);
    }
  }
}

__device__ __forceinline__ void store_tile(short* __restrict__ dst, int ldd, int nt,
                                           const float* __restrict__ bias,
                                           const f32x4 (&acc)[4], int l15, int l4,
                                           bool relu) {
  float bi = bias[nt * 16 + l15];
  #pragma unroll
  for (int rg = 0; rg < 4; ++rg)
    #pragma unroll
    for (int r = 0; r < 4; ++r) {
      float v = acc[rg][r] + bi;
      if (relu) v = fmaxf(v, 0.f);
      dst[(rg * 16 + l4 * 4 + r) * ldd + nt * 16 + l15] = f2bf(v);
    }
}

__global__ __launch_bounds__(256, 1)
void fused_main(const float* __restrict__ x, const int* __restrict__ cause,
                const char* __restrict__ ws,
                const float* __restrict__ b2c, const float* __restrict__ b2o,
                const float* __restrict__ b2p, const float* __restrict__ bh,
                float* __restrict__ out) {
  const short* W1cb = (const short*)(ws);
  const short* W2cb = (const short*)(ws + 557056);
  const short* W1ob = (const short*)(ws + 835584);
  const short* W2ob = (const short*)(ws + 1392640);
  const short* W1pb = (const short*)(ws + 1671168);
  const short* W2pb = (const short*)(ws + 1818624);
  const short* Whb  = (const short*)(ws + 1855488);
  const float* b1cp = (const float*)(ws + 1921024);
  const float* b1op = (const float*)(ws + 1923200);
  const float* b1pp = (const float*)(ws + 1925376);

  extern __shared__ __align__(16) char lds[];
  short* Cs    = (short*)lds;             // [64][264] (flushed after Xs dead)
  short* Os    = (short*)(lds + 33792);   // [64][264]
  short* Hs    = (short*)(lds + 67584);   // [64][552]
  short* Xs    = (short*)lds;             // [64][520] overlays Cs|Os
  float* headB = (float*)(lds + 67584);   // [64][68] f32 (after Hs dead)
  short* Hp    = (short*)(lds + 67584);   // [64][296]    (after headB dead)

  const int tid  = threadIdx.x;
  const int lane = tid & 63;
  const int wid  = tid >> 6;
  const int l15  = lane & 15;
  const int l4   = lane >> 4;            // 0..3
  const int rbase = wid * 16;            // row-split base (head/propL2 only)
  const size_t grow0 = (size_t)blockIdx.x * 64;

  // ---- stage X (f32 -> bf16), nontemporal to keep weights resident in L2 --
  {
    const f32x4* xsrc = (const f32x4*)(x + grow0 * 512);
    for (int i = tid; i < 8192; i += 256) {   // 64 rows * 128 float4
      f32x4 v = __builtin_nontemporal_load(xsrc + i);
      int r = i >> 7, c = i & 127;
      s16x4 p;
      p.x = f2bf(v.x); p.y = f2bf(v.y); p.z = f2bf(v.z); p.w = f2bf(v.w);
      *(s16x4*)&Xs[r * 520 + c * 4] = p;
    }
  }
  __syncthreads();   // B0: X staged

  // ---- L1c: Hs = relu(X @ W1c^T + b1c); 34 nt = 17 pairs ----
  for (int p = wid; p < 17; p += 4) {
    f32x4 a0[4], a1[4];
    pair_mm<16>(W1cb, 512, Xs, 520, 2 * p, l15, l4, a0, a1);
    store_tile(Hs, 552, 2 * p,     b1cp, a0, l15, l4, true);
    store_tile(Hs, 552, 2 * p + 1, b1cp, a1, l15, l4, true);
  }
  __syncthreads();   // B1: H_c complete

  // ---- L2c: crep = Hs @ W2c^T + b2c, kept packed-bf16 in regs (Xs alive!) -
  s16x4 crp[4][4];   // [jj][rg]: jj -> nt = {2w, 2w+1, 2w+8, 2w+9}
  {
    int jj = 0;
    for (int p = wid; p < 8; p += 4, jj += 2) {
      f32x4 a0[4], a1[4];
      pair_mm<17>(W2cb, 544, Hs, 552, 2 * p, l15, l4, a0, a1);
      float bi0 = b2c[p * 32 + l15], bi1 = b2c[p * 32 + 16 + l15];
      #pragma unroll
      for (int rg = 0; rg < 4; ++rg) {
        s16x4 q0, q1;
        #pragma unroll
        for (int r = 0; r < 4; ++r) {
          q0[r] = f2bf(a0[rg][r] + bi0);
          q1[r] = f2bf(a1[rg][r] + bi1);
        }
        crp[jj][rg] = q0; crp[jj + 1][rg] = q1;
      }
    }
  }
  __syncthreads();   // B2: Hs reads done -> L1o may overwrite

  // ---- L1o: Hs = relu(X @ W1o^T + b1o) ----
  for (int p = wid; p < 17; p += 4) {
    f32x4 a0[4], a1[4];
    pair_mm<16>(W1ob, 512, Xs, 520, 2 * p, l15, l4, a0, a1);
    store_tile(Hs, 552, 2 * p,     b1op, a0, l15, l4, true);
    store_tile(Hs, 552, 2 * p + 1, b1op, a1, l15, l4, true);
  }
  __syncthreads();   // B3: H_o complete; Xs dead everywhere

  // ---- flush crep -> Cs (region0, now free) ----
  {
    const int ntj[4] = {2 * wid, 2 * wid + 1, 2 * wid + 8, 2 * wid + 9};
    #pragma unroll
    for (int jj = 0; jj < 4; ++jj)
      #pragma unroll
      for (int rg = 0; rg < 4; ++rg)
        #pragma unroll
        for (int r = 0; r < 4; ++r)
          Cs[(rg * 16 + l4 * 4 + r) * 264 + ntj[jj] * 16 + l15] = crp[jj][rg][r];
  }

  // ---- L2o: Os = Hs @ W2o^T + b2o ----
  for (int p = wid; p < 8; p += 4) {
    f32x4 a0[4], a1[4];
    pair_mm<17>(W2ob, 544, Hs, 552, 2 * p, l15, l4, a0, a1);
    store_tile(Os, 264, 2 * p,     b2o, a0, l15, l4, false);
    store_tile(Os, 264, 2 * p + 1, b2o, a1, l15, l4, false);
  }
  __syncthreads();   // B4: Cs+Os complete; Hs dead

  // ---- head (row-split): pred[16 own rows][64] = [C|O] @ Wh^T ----
  f32x4 hacc[4] = {{0.f,0.f,0.f,0.f},{0.f,0.f,0.f,0.f},{0.f,0.f,0.f,0.f},{0.f,0.f,0.f,0.f}};
  {
    bf16x8 acf[16];
    #pragma unroll
    for (int kt = 0; kt < 8; ++kt) {
      acf[kt]     = *(const bf16x8*)&Cs[(rbase + l15) * 264 + kt * 32 + l4 * 8];
      acf[kt + 8] = *(const bf16x8*)&Os[(rbase + l15) * 264 + kt * 32 + l4 * 8];
    }
    #pragma unroll
    for (int nt = 0; nt < 4; ++nt) {
      const short* w0 = Whb + (nt * 16 + l15) * 512 + l4 * 8;
      #pragma unroll
      for (int kt = 0; kt < 16; ++kt)
        hacc[nt] = MFMA16(acf[kt], *(const bf16x8*)(w0 + kt * 32), hacc[nt], 0, 0, 0);
    }
  }
  // headB overlays Hs region (dead); wave writes/reads only its own 16 rows
  #pragma unroll
  for (int nt = 0; nt < 4; ++nt)
    #pragma unroll
    for (int r = 0; r < 4; ++r)
      headB[(rbase + l4 * 4 + r) * 68 + nt * 16 + l15] = hacc[nt][r];
  if (lane < 16) {
    int row = rbase + lane;
    size_t gr = grow0 + row;
    int cv = cause[gr];
    out[gr] = headB[row * 68 + cv] + bh[cv];
    out[(size_t)8519681 + gr] = (float)cv;
  }
  __syncthreads();   // B5: headB reads done -> Hp may overwrite

  // ---- propensity L1: Hp = relu(Cs @ W1p^T + b1p); 18 nt = 9 pairs ----
  for (int p = wid; p < 9; p += 4) {
    f32x4 a0[4], a1[4];
    pair_mm<8>(W1pb, 256, Cs, 264, 2 * p, l15, l4, a0, a1);
    store_tile(Hp, 296, 2 * p,     b1pp, a0, l15, l4, true);
    store_tile(Hp, 296, 2 * p + 1, b1pp, a1, l15, l4, true);
  }
  __syncthreads();   // B6: Hp complete

  // ---- propensity L2 + log_softmax (row-split, wave-local rows) ----
  f32x4 pl[4];
  {
    bf16x8 ahp[9];
    #pragma unroll
    for (int kt = 0; kt < 9; ++kt)
      ahp[kt] = *(const bf16x8*)&Hp[(rbase + l15) * 296 + kt * 32 + l4 * 8];
    #pragma unroll
    for (int nt = 0; nt < 4; ++nt) {
      f32x4 a0 = {0.f, 0.f, 0.f, 0.f};
      const short* w0 = W2pb + (nt * 16 + l15) * 288 + l4 * 8;
      #pragma unroll
      for (int kt = 0; kt < 9; ++kt)
        a0 = MFMA16(ahp[kt], *(const bf16x8*)(w0 + kt * 32), a0, 0, 0, 0);
      float bi = b2p[nt * 16 + l15];
      #pragma unroll
      for (int r = 0; r < 4; ++r) a0[r] += bi;
      pl[nt] = a0;
    }
  }
  #pragma unroll
  for (int r = 0; r < 4; ++r) {
    float m = fmaxf(fmaxf(pl[0][r], pl[1][r]), fmaxf(pl[2][r], pl[3][r]));
    m = fmaxf(m, __shfl_xor(m, 1, 64));
    m = fmaxf(m, __shfl_xor(m, 2, 64));
    m = fmaxf(m, __shfl_xor(m, 4, 64));
    m = fmaxf(m, __shfl_xor(m, 8, 64));
    float s = __expf(pl[0][r] - m) + __expf(pl[1][r] - m)
            + __expf(pl[2][r] - m) + __expf(pl[3][r] - m);
    s += __shfl_xor(s, 1, 64);
    s += __shfl_xor(s, 2, 64);
    s += __shfl_xor(s, 4, 64);
    s += __shfl_xor(s, 8, 64);
    float lse = m + __logf(s);
    size_t gr = grow0 + rbase + l4 * 4 + r;
    float* o1 = out + 131072 + gr * 64;
    #pragma unroll
    for (int nt = 0; nt < 4; ++nt)
      o1[nt * 16 + l15] = pl[nt][r] - lse;
  }
  if (blockIdx.x == 0 && tid == 0) out[8519680] = 0.0f;   // mmd
}

extern "C" void kernel_launch(void* const* d_in, const int* in_sizes, int n_in,
                              void* d_out, int out_size, void* d_ws, size_t ws_size,
                              hipStream_t stream) {
  (void)in_sizes; (void)n_in; (void)out_size; (void)ws_size;
  const float* x    = (const float*)d_in[0];
  const int*   cause= (const int*)  d_in[1];
  const float* W1c  = (const float*)d_in[2];
  const float* b1c  = (const float*)d_in[3];
  const float* W2c  = (const float*)d_in[4];
  const float* b2c  = (const float*)d_in[5];
  const float* W1o  = (const float*)d_in[6];
  const float* b1o  = (const float*)d_in[7];
  const float* W2o  = (const float*)d_in[8];
  const float* b2o  = (const float*)d_in[9];
  const float* W1p  = (const float*)d_in[10];
  const float* b1p  = (const float*)d_in[11];
  const float* W2p  = (const float*)d_in[12];
  const float* b2p  = (const float*)d_in[13];
  const float* Wh   = (const float*)d_in[14];
  const float* bh   = (const float*)d_in[15];
  char* ws = (char*)d_ws;

  prep_weights<<<3758, 256, 0, stream>>>(W1c, W2c, W1o, W2o, W1p, W2p, Wh,
                                         b1c, b1o, b1p, ws);

  (void)hipFuncSetAttribute((const void*)fused_main,
                            hipFuncAttributeMaxDynamicSharedMemorySize, 138240);
  fused_main<<<2048, 256, 138240, stream>>>(x, cause, ws, b2c, b2o, b2p, bh,
                                            (float*)d_out);
}

// Round 6
// 568.372 us; speedup vs baseline: 4.1639x; 1.6573x over previous
//
#include <hip/hip_runtime.h>

// ---------------------------------------------------------------------------
// DR_CRN_Multicause fused forward — round 6: 8 waves/block (2 waves/SIMD TLP)
//   nt-split + nt-paired tiles, A-operands from LDS, weights once per block.
//   B=131072, N_CONF=512, H1=513(->544), N_REP=256, HP=257(->288), N_TREAT=64
// out (FLOAT32): pred_sel[B] | log_prop[B*64] | mmd[1] | cause[B]
// LDS (138240 B): Cs[0,33792) | Os[33792,67584) | Hs[67584,138240)
//   Xs[64][520] overlays [0,66560) (alive stage -> end L1o; Cs flushed after)
//   headB/Hp overlay Hs region after L2o.
// ---------------------------------------------------------------------------

typedef __attribute__((ext_vector_type(8))) short bf16x8;
typedef __attribute__((ext_vector_type(4))) float f32x4;
typedef __attribute__((ext_vector_type(4))) short s16x4;

#define MFMA16 __builtin_amdgcn_mfma_f32_16x16x32_bf16

__device__ __forceinline__ short f2bf(float f) {
  union { float f; unsigned u; } v; v.f = f;
  return (short)((v.u + 0x7FFFu + ((v.u >> 16) & 1u)) >> 16);  // RNE
}

// ---- prep: convert+pad all weights/biases into ws (single launch) ----------
__global__ void prep_weights(const float* __restrict__ W1c, const float* __restrict__ W2c,
                             const float* __restrict__ W1o, const float* __restrict__ W2o,
                             const float* __restrict__ W1p, const float* __restrict__ W2p,
                             const float* __restrict__ Wh,
                             const float* __restrict__ b1c, const float* __restrict__ b1o,
                             const float* __restrict__ b1p,
                             char* __restrict__ ws) {
  int s = blockIdx.x * 256 + threadIdx.x;
  if (s < 960512) {                      // bf16 weight region (shorts)
    float v;
    if (s < 278528)      { int n = s >> 9,        k = s & 511;        v = (n < 513) ? W1c[n * 512 + k] : 0.f; }
    else if (s < 417792) { int i = s - 278528; int n = i / 544, k = i - n * 544; v = (k < 513) ? W2c[n * 513 + k] : 0.f; }
    else if (s < 696320) { int i = s - 417792; int n = i >> 9,  k = i & 511;     v = (n < 513) ? W1o[n * 512 + k] : 0.f; }
    else if (s < 835584) { int i = s - 696320; int n = i / 544, k = i - n * 544; v = (k < 513) ? W2o[n * 513 + k] : 0.f; }
    else if (s < 909312) { int i = s - 835584; int n = i >> 8,  k = i & 255;     v = (n < 257) ? W1p[n * 256 + k] : 0.f; }
    else if (s < 927744) { int i = s - 909312; int n = i / 288, k = i - n * 288; v = (k < 257) ? W2p[n * 257 + k] : 0.f; }
    else                 { v = Wh[s - 927744]; }
    ((short*)ws)[s] = f2bf(v);
  } else if (s < 961888) {               // padded f32 biases
    int j = s - 960512;
    float v;
    if (j < 544)       v = (j < 513) ? b1c[j] : 0.f;
    else if (j < 1088) { int q = j - 544;  v = (q < 513) ? b1o[q] : 0.f; }
    else               { int q = j - 1088; v = (q < 257) ? b1p[q] : 0.f; }
    ((float*)(ws + 1921024))[j] = v;
  }
}

// paired 2x16-col tile: B in regs, A from LDS; acc0 = cols [nt0*16,+16),
// acc1 = cols [nt0*16+16,+16), all 64 rows.
template<int NKT>
__device__ __forceinline__ void pair_mm(const short* __restrict__ W, int ldw,
                                        const short* __restrict__ A, int lda,
                                        int nt0, int l15, int l4,
                                        f32x4 (&acc0)[4], f32x4 (&acc1)[4]) {
  bf16x8 b0[NKT], b1[NKT];
  const short* w0 = W + (nt0 * 16 + l15) * ldw + l4 * 8;
  const short* w1 = w0 + 16 * ldw;
  #pragma unroll
  for (int kt = 0; kt < NKT; ++kt) {
    b0[kt] = *(const bf16x8*)(w0 + kt * 32);
    b1[kt] = *(const bf16x8*)(w1 + kt * 32);
  }
  #pragma unroll
  for (int rg = 0; rg < 4; ++rg) {
    acc0[rg] = (f32x4){0.f, 0.f, 0.f, 0.f};
    acc1[rg] = (f32x4){0.f, 0.f, 0.f, 0.f};
  }
  #pragma unroll
  for (int kt = 0; kt < NKT; ++kt) {
    #pragma unroll
    for (int rg = 0; rg < 4; ++rg) {
      bf16x8 a = *(const bf16x8*)(A + (rg * 16 + l15) * lda + kt * 32 + l4 * 8);
      acc0[rg] = MFMA16(a, b0[kt], acc0[rg], 0, 0, 0);
      acc1[rg] = MFMA16(a, b1[kt], acc1[rg], 0, 0, 0);
    }
  }
}

__device__ __forceinline__ void store_tile(short* __restrict__ dst, int ldd, int nt,
                                           const float* __restrict__ bias,
                                           const f32x4 (&acc)[4], int l15, int l4,
                                           bool relu) {
  float bi = bias[nt * 16 + l15];
  #pragma unroll
  for (int rg = 0; rg < 4; ++rg)
    #pragma unroll
    for (int r = 0; r < 4; ++r) {
      float v = acc[rg][r] + bi;
      if (relu) v = fmaxf(v, 0.f);
      dst[(rg * 16 + l4 * 4 + r) * ldd + nt * 16 + l15] = f2bf(v);
    }
}

__global__ __launch_bounds__(512, 1)
void fused_main(const float* __restrict__ x, const int* __restrict__ cause,
                const char* __restrict__ ws,
                const float* __restrict__ b2c, const float* __restrict__ b2o,
                const float* __restrict__ b2p, const float* __restrict__ bh,
                float* __restrict__ out) {
  const short* W1cb = (const short*)(ws);
  const short* W2cb = (const short*)(ws + 557056);
  const short* W1ob = (const short*)(ws + 835584);
  const short* W2ob = (const short*)(ws + 1392640);
  const short* W1pb = (const short*)(ws + 1671168);
  const short* W2pb = (const short*)(ws + 1818624);
  const short* Whb  = (const short*)(ws + 1855488);
  const float* b1cp = (const float*)(ws + 1921024);
  const float* b1op = (const float*)(ws + 1923200);
  const float* b1pp = (const float*)(ws + 1925376);

  extern __shared__ __align__(16) char lds[];
  short* Cs    = (short*)lds;             // [64][264] (flushed after Xs dead)
  short* Os    = (short*)(lds + 33792);   // [64][264]
  short* Hs    = (short*)(lds + 67584);   // [64][552]
  short* Xs    = (short*)lds;             // [64][520] overlays Cs|Os
  float* headB = (float*)(lds + 67584);   // [64][68] f32 (after Hs dead)
  short* Hp    = (short*)(lds + 67584);   // [64][296]    (after headB dead)

  const int tid  = threadIdx.x;
  const int lane = tid & 63;
  const int wid  = tid >> 6;             // 0..7
  const int l15  = lane & 15;
  const int l4   = lane >> 4;            // 0..3
  const size_t grow0 = (size_t)blockIdx.x * 64;

  // ---- stage X (f32 -> bf16), nontemporal to keep weights resident in L2 --
  {
    const f32x4* xsrc = (const f32x4*)(x + grow0 * 512);
    for (int i = tid; i < 8192; i += 512) {   // 64 rows * 128 float4
      f32x4 v = __builtin_nontemporal_load(xsrc + i);
      int r = i >> 7, c = i & 127;
      s16x4 p;
      p.x = f2bf(v.x); p.y = f2bf(v.y); p.z = f2bf(v.z); p.w = f2bf(v.w);
      *(s16x4*)&Xs[r * 520 + c * 4] = p;
    }
  }
  __syncthreads();   // B0: X staged

  // ---- L1c: Hs = relu(X @ W1c^T + b1c); 34 nt = 17 pairs over 8 waves ----
  for (int p = wid; p < 17; p += 8) {
    f32x4 a0[4], a1[4];
    pair_mm<16>(W1cb, 512, Xs, 520, 2 * p, l15, l4, a0, a1);
    store_tile(Hs, 552, 2 * p,     b1cp, a0, l15, l4, true);
    store_tile(Hs, 552, 2 * p + 1, b1cp, a1, l15, l4, true);
  }
  __syncthreads();   // B1: H_c complete

  // ---- L2c: crep = Hs @ W2c^T + b2c; 8 pairs -> exactly 1 per wave.
  //      Kept packed-bf16 in regs (Xs still alive in region0/1). ----
  s16x4 crp[2][4];   // [jj][rg]: nt = 2*wid + jj
  {
    f32x4 a0[4], a1[4];
    pair_mm<17>(W2cb, 544, Hs, 552, 2 * wid, l15, l4, a0, a1);
    float bi0 = b2c[wid * 32 + l15], bi1 = b2c[wid * 32 + 16 + l15];
    #pragma unroll
    for (int rg = 0; rg < 4; ++rg) {
      s16x4 q0, q1;
      #pragma unroll
      for (int r = 0; r < 4; ++r) {
        q0[r] = f2bf(a0[rg][r] + bi0);
        q1[r] = f2bf(a1[rg][r] + bi1);
      }
      crp[0][rg] = q0; crp[1][rg] = q1;
    }
  }
  __syncthreads();   // B2: Hs reads done -> L1o may overwrite

  // ---- L1o: Hs = relu(X @ W1o^T + b1o) ----
  for (int p = wid; p < 17; p += 8) {
    f32x4 a0[4], a1[4];
    pair_mm<16>(W1ob, 512, Xs, 520, 2 * p, l15, l4, a0, a1);
    store_tile(Hs, 552, 2 * p,     b1op, a0, l15, l4, true);
    store_tile(Hs, 552, 2 * p + 1, b1op, a1, l15, l4, true);
  }
  __syncthreads();   // B3: H_o complete; Xs dead everywhere

  // ---- flush crep -> Cs (region0, now free) ----
  #pragma unroll
  for (int jj = 0; jj < 2; ++jj) {
    int nt = 2 * wid + jj;
    #pragma unroll
    for (int rg = 0; rg < 4; ++rg)
      #pragma unroll
      for (int r = 0; r < 4; ++r)
        Cs[(rg * 16 + l4 * 4 + r) * 264 + nt * 16 + l15] = crp[jj][rg][r];
  }

  // ---- L2o: Os = Hs @ W2o^T + b2o; 1 pair per wave ----
  {
    f32x4 a0[4], a1[4];
    pair_mm<17>(W2ob, 544, Hs, 552, 2 * wid, l15, l4, a0, a1);
    store_tile(Os, 264, 2 * wid,     b2o, a0, l15, l4, false);
    store_tile(Os, 264, 2 * wid + 1, b2o, a1, l15, l4, false);
  }
  __syncthreads();   // B4: Cs+Os complete; Hs dead

  // ---- head: wave pair (g = wid>>1) shares 16-row group, splits 4 nt 2/2 --
  {
    const int g = wid >> 1;
    const int rb = g * 16;
    const int ntb = (wid & 1) * 2;
    bf16x8 acf[16];
    #pragma unroll
    for (int kt = 0; kt < 8; ++kt) {
      acf[kt]     = *(const bf16x8*)&Cs[(rb + l15) * 264 + kt * 32 + l4 * 8];
      acf[kt + 8] = *(const bf16x8*)&Os[(rb + l15) * 264 + kt * 32 + l4 * 8];
    }
    f32x4 hacc[2] = {{0.f,0.f,0.f,0.f},{0.f,0.f,0.f,0.f}};
    #pragma unroll
    for (int j = 0; j < 2; ++j) {
      const short* w0 = Whb + ((ntb + j) * 16 + l15) * 512 + l4 * 8;
      #pragma unroll
      for (int kt = 0; kt < 16; ++kt)
        hacc[j] = MFMA16(acf[kt], *(const bf16x8*)(w0 + kt * 32), hacc[j], 0, 0, 0);
    }
    // headB overlays Hs region (dead after B4)
    #pragma unroll
    for (int j = 0; j < 2; ++j)
      #pragma unroll
      for (int r = 0; r < 4; ++r)
        headB[(rb + l4 * 4 + r) * 68 + (ntb + j) * 16 + l15] = hacc[j][r];
  }
  __syncthreads();   // B5: headB complete (nt halves from both waves of pair)

  // one-hot selection + cause passthrough: waves 0..3 handle 16 rows each
  if (wid < 4 && lane < 16) {
    int row = wid * 16 + lane;
    size_t gr = grow0 + row;
    int cv = cause[gr];
    out[gr] = headB[row * 68 + cv] + bh[cv];
    out[(size_t)8519681 + gr] = (float)cv;
  }
  __syncthreads();   // B6: selection reads done -> Hp may overwrite

  // ---- propensity L1: Hp = relu(Cs @ W1p^T + b1p); 9 pairs over 8 waves ---
  for (int p = wid; p < 9; p += 8) {
    f32x4 a0[4], a1[4];
    pair_mm<8>(W1pb, 256, Cs, 264, 2 * p, l15, l4, a0, a1);
    store_tile(Hp, 296, 2 * p,     b1pp, a0, l15, l4, true);
    store_tile(Hp, 296, 2 * p + 1, b1pp, a1, l15, l4, true);
  }
  __syncthreads();   // B7: Hp complete

  // ---- propensity L2 + log_softmax: waves 0..3, one 16-row group each ----
  if (wid < 4) {
    const int rb = wid * 16;
    f32x4 pl[4];
    {
      bf16x8 ahp[9];
      #pragma unroll
      for (int kt = 0; kt < 9; ++kt)
        ahp[kt] = *(const bf16x8*)&Hp[(rb + l15) * 296 + kt * 32 + l4 * 8];
      #pragma unroll
      for (int nt = 0; nt < 4; ++nt) {
        f32x4 a0 = {0.f, 0.f, 0.f, 0.f};
        const short* w0 = W2pb + (nt * 16 + l15) * 288 + l4 * 8;
        #pragma unroll
        for (int kt = 0; kt < 9; ++kt)
          a0 = MFMA16(ahp[kt], *(const bf16x8*)(w0 + kt * 32), a0, 0, 0, 0);
        float bi = b2p[nt * 16 + l15];
        #pragma unroll
        for (int r = 0; r < 4; ++r) a0[r] += bi;
        pl[nt] = a0;
      }
    }
    #pragma unroll
    for (int r = 0; r < 4; ++r) {
      float m = fmaxf(fmaxf(pl[0][r], pl[1][r]), fmaxf(pl[2][r], pl[3][r]));
      m = fmaxf(m, __shfl_xor(m, 1, 64));
      m = fmaxf(m, __shfl_xor(m, 2, 64));
      m = fmaxf(m, __shfl_xor(m, 4, 64));
      m = fmaxf(m, __shfl_xor(m, 8, 64));
      float s = __expf(pl[0][r] - m) + __expf(pl[1][r] - m)
              + __expf(pl[2][r] - m) + __expf(pl[3][r] - m);
      s += __shfl_xor(s, 1, 64);
      s += __shfl_xor(s, 2, 64);
      s += __shfl_xor(s, 4, 64);
      s += __shfl_xor(s, 8, 64);
      float lse = m + __logf(s);
      size_t gr = grow0 + rb + l4 * 4 + r;
      float* o1 = out + 131072 + gr * 64;
      #pragma unroll
      for (int nt = 0; nt < 4; ++nt)
        o1[nt * 16 + l15] = pl[nt][r] - lse;
    }
  }
  if (blockIdx.x == 0 && tid == 0) out[8519680] = 0.0f;   // mmd
}

extern "C" void kernel_launch(void* const* d_in, const int* in_sizes, int n_in,
                              void* d_out, int out_size, void* d_ws, size_t ws_size,
                              hipStream_t stream) {
  (void)in_sizes; (void)n_in; (void)out_size; (void)ws_size;
  const float* x    = (const float*)d_in[0];
  const int*   cause= (const int*)  d_in[1];
  const float* W1c  = (const float*)d_in[2];
  const float* b1c  = (const float*)d_in[3];
  const float* W2c  = (const float*)d_in[4];
  const float* b2c  = (const float*)d_in[5];
  const float* W1o  = (const float*)d_in[6];
  const float* b1o  = (const float*)d_in[7];
  const float* W2o  = (const float*)d_in[8];
  const float* b2o  = (const float*)d_in[9];
  const float* W1p  = (const float*)d_in[10];
  const float* b1p  = (const float*)d_in[11];
  const float* W2p  = (const float*)d_in[12];
  const float* b2p  = (const float*)d_in[13];
  const float* Wh   = (const float*)d_in[14];
  const float* bh   = (const float*)d_in[15];
  char* ws = (char*)d_ws;

  prep_weights<<<3758, 256, 0, stream>>>(W1c, W2c, W1o, W2o, W1p, W2p, Wh,
                                         b1c, b1o, b1p, ws);

  (void)hipFuncSetAttribute((const void*)fused_main,
                            hipFuncAttributeMaxDynamicSharedMemorySize, 138240);
  fused_main<<<2048, 512, 138240, stream>>>(x, cause, ws, b2c, b2o, b2p, bh,
                                            (float*)d_out);
}